// Round 7
// baseline (55.307 us; speedup 1.0000x reference)
//
#include <hip/hip_runtime.h>

// Problem constants (from reference setup_inputs)
#define N_  16
#define C_  64
#define H_  128
#define W_  128
#define HO_ 64
#define WO_ 64
#define CO_ 18   // G*K*K = 2*3*3
#define NSP 8          // channel splits (= waves per block)
#define CPS (C_/NSP)   // 8 channels per split

__global__ __launch_bounds__(512, 4)   // allow up to 128 VGPR
void pasa_fused4(const float* __restrict__ x,
                 const float* __restrict__ cw,
                 const float* __restrict__ gamma,
                 const float* __restrict__ beta,
                 const float* __restrict__ mean,
                 const float* __restrict__ var,
                 float* __restrict__ out)
{
    // partial conv logits: [split][o][wo] = 8*18*64*4 = 36864 B
    __shared__ float part[NSP][CO_][WO_];

    const int tid = threadIdx.x;
    const int wo  = tid & 63;          // lane -> output col
    const int sp  = tid >> 6;          // wave id = channel split, 0..7
    // XCD-chunk swizzle: XCD = (bx + 64*by) % 8 = bx & 7; give each XCD
    // 8 contiguous ho rows so window rows stay L2-resident.
    const int bx  = blockIdx.x;
    const int ho  = ((bx & 7) << 3) | (bx >> 3);
    const int n   = blockIdx.y;

    // 3x3 window at input (2ho, 2wo), reflect pad=1 (only -1 reachable -> +1)
    int r0 = 2*ho - 1; if (r0 < 0) r0 = 1;
    const int r1 = 2*ho, r2 = 2*ho + 1;
    const int c1 = 2*wo;
    int c0 = c1 - 1; if (c0 < 0) c0 = 1;

    const float* __restrict__ xn = x + (size_t)n * (C_*H_*W_);

    // All window values for this wave's 8 channels -> registers (72 floats).
    // The o-outer conv loop below uses every element each iteration, so the
    // compiler cannot sink these loads; they must stay in VGPRs.
    float wv[CPS][9];
#pragma unroll
    for (int j = 0; j < CPS; ++j) {
        const int c = sp * CPS + j;
        const float* __restrict__ xc = xn + c * (H_*W_);
        wv[j][0] = xc[r0*W_ + c0];
        float2 t = *(const float2*)(xc + r0*W_ + c1);   // 8B aligned
        wv[j][1] = t.x; wv[j][2] = t.y;
        wv[j][3] = xc[r1*W_ + c0];
        t = *(const float2*)(xc + r1*W_ + c1);
        wv[j][4] = t.x; wv[j][5] = t.y;
        wv[j][6] = xc[r2*W_ + c0];
        t = *(const float2*)(xc + r2*W_ + c1);
        wv[j][7] = t.x; wv[j][8] = t.y;
    }

    // Weight base for this wave's channel block (uniform -> scalar loads).
    // For fixed o, the 8 channels' weights are 72 CONTIGUOUS floats:
    // cw[o*576 + (cbase+j)*9 + k]  ->  s_load_dwordx16 friendly.
    const int cbase = __builtin_amdgcn_readfirstlane(sp * CPS);
    const float* __restrict__ wbase = cw + cbase * 9;

    float sig[CO_];
    // Pass 1: o-outer / j-inner. 8 independent 9-FMA chains per o + add tree.
#pragma unroll
    for (int o = 0; o < CO_; ++o) {
        const float* __restrict__ q = wbase + o * 576;  // q[j*9 + k]
        float t[CPS];
#pragma unroll
        for (int j = 0; j < CPS; ++j) {
            float a = wv[j][0] * q[j*9 + 0];
#pragma unroll
            for (int k = 1; k < 9; ++k) a = fmaf(wv[j][k], q[j*9 + k], a);
            t[j] = a;
        }
        sig[o] = ((t[0]+t[1]) + (t[2]+t[3])) + ((t[4]+t[5]) + (t[6]+t[7]));
    }

    // Reduce the 8 partials (tree over sp; sp is wave-uniform -> no divergence)
#pragma unroll
    for (int o = 0; o < CO_; ++o) part[sp][o][wo] = sig[o];
    __syncthreads();
    if (sp < 4) {
#pragma unroll
        for (int o = 0; o < CO_; ++o) part[sp][o][wo] += part[sp+4][o][wo];
    }
    __syncthreads();
    if (sp < 2) {
#pragma unroll
        for (int o = 0; o < CO_; ++o) part[sp][o][wo] += part[sp+2][o][wo];
    }
    __syncthreads();
    if (sp == 0) {
#pragma unroll
        for (int o = 0; o < CO_; ++o) part[0][o][wo] += part[1][o][wo];
    }
    __syncthreads();

    // BN (folded) + softmax over 18 channels, redundant per thread (cheap)
    float mx = -3.4e38f;
#pragma unroll
    for (int o = 0; o < CO_; ++o) {
        const float inv = gamma[o] * rsqrtf(var[o] + 1e-5f);
        sig[o] = part[0][o][wo] * inv + (beta[o] - mean[o] * inv);
        mx = fmaxf(mx, sig[o]);
    }
    float sum = 0.f;
#pragma unroll
    for (int o = 0; o < CO_; ++o) { sig[o] = __expf(sig[o] - mx); sum += sig[o]; }
    const float rs = 1.f / sum;

    // Group-select with compile-time sig[] indices (g = sp>>2 is wave-uniform)
    float p[9];
    if ((sp >> 2) == 0) {
#pragma unroll
        for (int k = 0; k < 9; ++k) p[k] = sig[k] * rs;
    } else {
#pragma unroll
        for (int k = 0; k < 9; ++k) p[k] = sig[9 + k] * rs;
    }

    // Pass 2: softmax-weighted aggregation straight from registers (no loads).
#pragma unroll
    for (int j = 0; j < CPS; ++j) {
        const int c = sp * CPS + j;
        float acc = wv[j][0] * p[0];
#pragma unroll
        for (int k = 1; k < 9; ++k) acc = fmaf(wv[j][k], p[k], acc);
        out[(((size_t)n*C_ + c)*HO_ + ho)*WO_ + wo] = acc;
    }
}

extern "C" void kernel_launch(void* const* d_in, const int* in_sizes, int n_in,
                              void* d_out, int out_size, void* d_ws, size_t ws_size,
                              hipStream_t stream) {
    const float* x     = (const float*)d_in[0];
    const float* cw    = (const float*)d_in[1];
    const float* gamma = (const float*)d_in[2];
    const float* beta  = (const float*)d_in[3];
    const float* mean  = (const float*)d_in[4];
    const float* var   = (const float*)d_in[5];
    float* out = (float*)d_out;

    dim3 grid(HO_, N_);   // 64 ho-rows x 16 batch, 8 waves/block
    pasa_fused4<<<grid, 512, 0, stream>>>(x, cw, gamma, beta, mean, var, out);
}